// Round 1
// baseline (83.214 us; speedup 1.0000x reference)
//
#include <hip/hip_runtime.h>
#include <math.h>

#define KK 8
#define DD 8
#define TRI 36
#define PHI_DIM 360
#define MM 32
#define NN 32768
#define GX 16          // N-tiles
#define TPB 256
#define PP 4           // points per thread per pass
// points per pass per block = TPB*PP = 1024; N/GX = 2048 -> 2 passes

// out[m] = LAMBDA_PRIOR * 0.5 * sum(phi[m]^2); also initializes out (poisoned by harness)
__global__ void prior_kernel(const float* __restrict__ phi, float* __restrict__ out) {
    int m = blockIdx.x;
    const float* p = phi + m * PHI_DIM;
    float s = 0.f;
    for (int j = threadIdx.x; j < PHI_DIM; j += 64) {
        float v = p[j];
        s += v * v;
    }
    #pragma unroll
    for (int off = 32; off; off >>= 1) s += __shfl_down(s, off, 64);
    if (threadIdx.x == 0) out[m] = 0.01f * 0.5f * s;
}

__launch_bounds__(TPB)
__global__ void gmm_kernel(const float* __restrict__ phi, const float* __restrict__ X,
                           float* __restrict__ out) {
    __shared__ float s_mu[KK][DD];
    __shared__ float s_L[KK][TRI];   // diag replaced by reciprocal
    __shared__ float s_c[KK];        // log_pi + log_norm_const
    __shared__ float s_pi[KK];
    __shared__ float s_red[TPB / 64];

    const int m = blockIdx.y;
    const float* ph = phi + m * PHI_DIM;
    const int tid = threadIdx.x;

    if (tid < KK) {
        const int k = tid;
        s_pi[k] = ph[k];
        #pragma unroll
        for (int i = 0; i < DD; i++) s_mu[k][i] = ph[KK + k * DD + i];
        #pragma unroll
        for (int t = 0; t < TRI; t++) s_L[k][t] = ph[KK + KK * DD + k * TRI + t];
        float logdet = 0.f;
        #pragma unroll
        for (int i = 0; i < DD; i++) {
            const int di = i * (i + 1) / 2 + i;
            float dv = s_L[k][di];
            logdet += 2.f * logf(fmaxf(fabsf(dv), 1e-8f));
            s_L[k][di] = 1.f / dv;              // signed reciprocal for the solve
        }
        // -0.5*(D*log(2pi) + logdet)
        s_c[k] = -0.5f * (8.f * 1.8378770664093453f + logdet);
    }
    __syncthreads();
    if (tid < KK) {
        // log-softmax over pi_tilde (8 values, redundant per thread is fine)
        float mx = s_pi[0];
        #pragma unroll
        for (int i = 1; i < KK; i++) mx = fmaxf(mx, s_pi[i]);
        float sum = 0.f;
        #pragma unroll
        for (int i = 0; i < KK; i++) sum += expf(s_pi[i] - mx);
        float lse = mx + logf(sum);
        s_c[tid] += s_pi[tid] - lse;
    }
    __syncthreads();

    float acc = 0.f;
    const int base0 = blockIdx.x * (NN / GX);
    #pragma unroll 1
    for (int pass = 0; pass < (NN / GX) / (TPB * PP); ++pass) {
        const int n0 = base0 + pass * TPB * PP + tid;

        float x[PP][DD];
        #pragma unroll
        for (int p = 0; p < PP; p++) {
            const float4* xp = (const float4*)(X + (size_t)(n0 + p * TPB) * DD);
            float4 u0 = xp[0], u1 = xp[1];
            x[p][0] = u0.x; x[p][1] = u0.y; x[p][2] = u0.z; x[p][3] = u0.w;
            x[p][4] = u1.x; x[p][5] = u1.y; x[p][6] = u1.z; x[p][7] = u1.w;
        }

        float mrun[PP], srun[PP];
        #pragma unroll
        for (int p = 0; p < PP; p++) { mrun[p] = -INFINITY; srun[p] = 0.f; }

        #pragma unroll
        for (int k = 0; k < KK; k++) {
            float mu[DD], L[TRI];
            #pragma unroll
            for (int i = 0; i < DD; i++) mu[i] = s_mu[k][i];
            #pragma unroll
            for (int t = 0; t < TRI; t++) L[t] = s_L[k][t];
            const float c = s_c[k];

            #pragma unroll
            for (int p = 0; p < PP; p++) {
                float a[DD];
                float maha = 0.f;
                #pragma unroll
                for (int i = 0; i < DD; i++) {
                    float t = x[p][i] - mu[i];
                    #pragma unroll
                    for (int j = 0; j < i; j++)
                        t = fmaf(-L[i * (i + 1) / 2 + j], a[j], t);
                    a[i] = t * L[i * (i + 1) / 2 + i];
                    maha = fmaf(a[i], a[i], maha);
                }
                const float v = c - 0.5f * maha;
                const float mnew = fmaxf(mrun[p], v);
                srun[p] = srun[p] * __expf(mrun[p] - mnew) + __expf(v - mnew);
                mrun[p] = mnew;
            }
        }
        #pragma unroll
        for (int p = 0; p < PP; p++) acc += mrun[p] + __logf(srun[p]);
    }

    // block reduction -> atomicAdd(-sum) into out[m]
    #pragma unroll
    for (int off = 32; off; off >>= 1) acc += __shfl_down(acc, off, 64);
    if ((tid & 63) == 0) s_red[tid >> 6] = acc;
    __syncthreads();
    if (tid == 0) {
        float t = s_red[0] + s_red[1] + s_red[2] + s_red[3];
        atomicAdd(&out[m], -t);
    }
}

extern "C" void kernel_launch(void* const* d_in, const int* in_sizes, int n_in,
                              void* d_out, int out_size, void* d_ws, size_t ws_size,
                              hipStream_t stream) {
    const float* phi = (const float*)d_in[0];
    const float* X   = (const float*)d_in[1];
    float* out = (float*)d_out;

    prior_kernel<<<MM, 64, 0, stream>>>(phi, out);
    dim3 grid(GX, MM);
    gmm_kernel<<<grid, TPB, 0, stream>>>(phi, X, out);
}

// Round 2
// 72.100 us; speedup vs baseline: 1.1541x; 1.1541x over previous
//
#include <hip/hip_runtime.h>
#include <math.h>

#define KK 8
#define DD 8
#define TRI 36
#define PHI_DIM 360
#define MM 32
#define NN 32768
#define GX 32          // N-tiles -> NN/GX = 1024 = TPB*PP, exactly one pass
#define TPB 256
#define PP 4           // points per thread

// Single fused kernel. out[] must be zeroed first (hipMemsetAsync in launch).
// Params packed per (k): [0..7]=mu, [8..43]=L (diag replaced by reciprocal),
// [44] = log_pi_k - 0.5*(D*log(2pi) + logdet). Row stride 48 floats keeps
// each k-row 16B-aligned so LDS reads vectorize to ds_read_b128.
__launch_bounds__(TPB)
__global__ void gmm_kernel(const float* __restrict__ phi, const float* __restrict__ X,
                           float* __restrict__ out) {
    __shared__ float s_par[KK][48];
    __shared__ float s_red[TPB / 64];

    const int m = blockIdx.y;
    const float* __restrict__ ph = phi + m * PHI_DIM;
    const int tid = threadIdx.x;

    if (tid < KK) {
        const int k = tid;
        #pragma unroll
        for (int i = 0; i < DD; i++) s_par[k][i] = ph[KK + k * DD + i];
        #pragma unroll
        for (int t = 0; t < TRI; t++) s_par[k][8 + t] = ph[KK + KK * DD + k * TRI + t];
        float logdet = 0.f;
        #pragma unroll
        for (int i = 0; i < DD; i++) {
            const int di = 8 + i * (i + 1) / 2 + i;
            float dv = s_par[k][di];
            logdet += 2.f * __logf(fmaxf(fabsf(dv), 1e-8f));
            s_par[k][di] = 1.f / dv;          // signed reciprocal for the solve
        }
        // log-softmax over pi_tilde, computed redundantly by each of 8 threads
        float mx = ph[0];
        #pragma unroll
        for (int i = 1; i < KK; i++) mx = fmaxf(mx, ph[i]);
        float sum = 0.f;
        #pragma unroll
        for (int i = 0; i < KK; i++) sum += __expf(ph[i] - mx);
        const float lse = mx + __logf(sum);
        s_par[k][44] = (ph[k] - lse) - 0.5f * (8.f * 1.8378770664093453f + logdet);
    }

    // prior term: only the x==0 block column computes it (256 threads, strided)
    float pr = 0.f;
    if (blockIdx.x == 0) {
        for (int j = tid; j < PHI_DIM; j += TPB) {
            float v = ph[j];
            pr = fmaf(v, v, pr);
        }
    }
    __syncthreads();

    // load PP points per thread (two float4 each, fully coalesced)
    const int n0 = blockIdx.x * (NN / GX) + tid;
    float x[PP][DD];
    #pragma unroll
    for (int p = 0; p < PP; p++) {
        const float4* xp = (const float4*)(X + (size_t)(n0 + p * TPB) * DD);
        float4 u0 = xp[0], u1 = xp[1];
        x[p][0] = u0.x; x[p][1] = u0.y; x[p][2] = u0.z; x[p][3] = u0.w;
        x[p][4] = u1.x; x[p][5] = u1.y; x[p][6] = u1.z; x[p][7] = u1.w;
    }

    float v[PP][KK];
    #pragma unroll
    for (int k = 0; k < KK; k++) {
        float par[45];
        #pragma unroll
        for (int t = 0; t < 45; t++) par[t] = s_par[k][t];   // -> ds_read_b128 x12

        #pragma unroll
        for (int p = 0; p < PP; p++) {
            float a[DD];
            float maha = 0.f;
            #pragma unroll
            for (int i = 0; i < DD; i++) {
                float t = x[p][i] - par[i];
                #pragma unroll
                for (int j = 0; j < i; j++)
                    t = fmaf(-par[8 + i * (i + 1) / 2 + j], a[j], t);
                a[i] = t * par[8 + i * (i + 1) / 2 + i];
                maha = fmaf(a[i], a[i], maha);
            }
            v[p][k] = par[44] - 0.5f * maha;
        }
    }

    // deferred logsumexp over K=8 per point (8 exps instead of 16)
    float acc = 0.f;
    #pragma unroll
    for (int p = 0; p < PP; p++) {
        float mx = v[p][0];
        #pragma unroll
        for (int i = 1; i < KK; i++) mx = fmaxf(mx, v[p][i]);
        float s = 0.f;
        #pragma unroll
        for (int i = 0; i < KK; i++) s += __expf(v[p][i] - mx);
        acc += mx + __logf(s);
    }

    // per-thread contribution to out[m]: prior part minus log-lik part
    float contrib = 0.005f * pr - acc;   // LAMBDA_PRIOR * 0.5 = 0.005

    #pragma unroll
    for (int off = 32; off; off >>= 1) contrib += __shfl_down(contrib, off, 64);
    if ((tid & 63) == 0) s_red[tid >> 6] = contrib;
    __syncthreads();
    if (tid == 0) {
        float t = s_red[0] + s_red[1] + s_red[2] + s_red[3];
        atomicAdd(&out[m], t);
    }
}

extern "C" void kernel_launch(void* const* d_in, const int* in_sizes, int n_in,
                              void* d_out, int out_size, void* d_ws, size_t ws_size,
                              hipStream_t stream) {
    const float* phi = (const float*)d_in[0];
    const float* X   = (const float*)d_in[1];
    float* out = (float*)d_out;

    hipMemsetAsync(out, 0, out_size * sizeof(float), stream);
    dim3 grid(GX, MM);
    gmm_kernel<<<grid, TPB, 0, stream>>>(phi, X, out);
}